// Round 1
// 355.957 us; speedup vs baseline: 1.3961x; 1.3961x over previous
//
#include <hip/hip_runtime.h>

// NaturalVariation: out = x + softmax(x@W_sel + b_sel)@patterns + EMA(0.05*noise)
// B=4, T=8192, H=1024, P=8. fp32 in/out. Ideal traffic ~447 MB -> ~71 us floor.
//
// EMA truncation: 0.9^64 = 1.18e-3 -> worst-case dropped tail
// <= 0.05*|noise|max*0.9^65/0.1 ~ 3.5e-4 << 0.11 threshold. So chunks of
// T are independent given a 64-step warm-up -> no serial scan, no carries.
//
// R1 changes vs 497us baseline:
//  - kB: H split 4 ways -> 1024 blocks (16 waves/CU, was 4). Kernel was
//    latency-bound at 1 wave/SIMD (Occ 10.4%, VALUBusy 3.9%, HBM 22%).
//  - kA: lane->h remap (h = r*64+lane). Old layout gathered W_sel at
//    128B lane stride = 64 cache lines per instruction; now x is dword-
//    coalesced and W rows are float4 pairs at 32B stride (span fully used).
//    2 tokens per wave to halve W_sel L1 traffic.

#define T_LEN 8192
#define H_DIM 1024
#define B_DIM 4
#define NPAT 8
#define CHUNK 128            // tokens per kB block
#define WARM 64              // EMA warm-up steps
#define NCHUNK (T_LEN / CHUNK)   // 64 chunks per batch row
#define HSPLIT 4             // kB blocks per chunk (H slices)
#define HSL (H_DIM / HSPLIT) // 256 columns per block

static_assert(WARM < CHUNK, "warm-up must stay within previous chunk");

// ---------------- Kernel A: per-token softmax weights --------------------
// 4 waves/block, 2 tokens per wave. Lane l covers h = r*64 + l, r=0..15.
__global__ __launch_bounds__(256) void kA_weights(
    const float* __restrict__ x, const float* __restrict__ Wsel,
    const float* __restrict__ bsel, float* __restrict__ wts)
{
    const int wave = threadIdx.x >> 6;
    const int lane = threadIdx.x & 63;
    const int tok0 = blockIdx.x * 8 + wave * 2;    // 2 tokens per wave
    const float* x0 = x + (size_t)tok0 * H_DIM;
    const float* x1 = x0 + H_DIM;

    float a0[NPAT], a1[NPAT];
#pragma unroll
    for (int p = 0; p < NPAT; ++p) { a0[p] = 0.0f; a1[p] = 0.0f; }

#pragma unroll
    for (int r = 0; r < 16; ++r) {
        const int h = r * 64 + lane;
        // W row: 8 floats at 32B lane stride -> 2KB contiguous span, fully used
        const float4 wa = *(const float4*)(Wsel + (size_t)h * NPAT);
        const float4 wb = *(const float4*)(Wsel + (size_t)h * NPAT + 4);
        const float v0 = x0[h];                    // dword, 256B/wave coalesced
        const float v1 = x1[h];
        a0[0] = fmaf(v0, wa.x, a0[0]);  a1[0] = fmaf(v1, wa.x, a1[0]);
        a0[1] = fmaf(v0, wa.y, a0[1]);  a1[1] = fmaf(v1, wa.y, a1[1]);
        a0[2] = fmaf(v0, wa.z, a0[2]);  a1[2] = fmaf(v1, wa.z, a1[2]);
        a0[3] = fmaf(v0, wa.w, a0[3]);  a1[3] = fmaf(v1, wa.w, a1[3]);
        a0[4] = fmaf(v0, wb.x, a0[4]);  a1[4] = fmaf(v1, wb.x, a1[4]);
        a0[5] = fmaf(v0, wb.y, a0[5]);  a1[5] = fmaf(v1, wb.y, a1[5]);
        a0[6] = fmaf(v0, wb.z, a0[6]);  a1[6] = fmaf(v1, wb.z, a1[6]);
        a0[7] = fmaf(v0, wb.w, a0[7]);  a1[7] = fmaf(v1, wb.w, a1[7]);
    }

    // full-wave butterfly reduction of 2x8 partials
#pragma unroll
    for (int off = 1; off < 64; off <<= 1) {
#pragma unroll
        for (int p = 0; p < NPAT; ++p) {
            a0[p] += __shfl_xor(a0[p], off, 64);
            a1[p] += __shfl_xor(a1[p], off, 64);
        }
    }

#pragma unroll
    for (int p = 0; p < NPAT; ++p) {   // TEMPERATURE == 1.0
        a0[p] += bsel[p];
        a1[p] += bsel[p];
    }

    // softmax (redundant on all lanes; lane 0 stores both tokens)
    float m0 = a0[0], m1 = a1[0];
#pragma unroll
    for (int p = 1; p < NPAT; ++p) { m0 = fmaxf(m0, a0[p]); m1 = fmaxf(m1, a1[p]); }
    float e0[NPAT], e1[NPAT], s0 = 0.0f, s1 = 0.0f;
#pragma unroll
    for (int p = 0; p < NPAT; ++p) {
        e0[p] = __expf(a0[p] - m0); s0 += e0[p];
        e1[p] = __expf(a1[p] - m1); s1 += e1[p];
    }
    const float i0 = 1.0f / s0, i1 = 1.0f / s1;

    if (lane == 0) {
        float* wp = wts + (size_t)tok0 * NPAT;
        *(float4*)(wp + 0)  = make_float4(e0[0]*i0, e0[1]*i0, e0[2]*i0, e0[3]*i0);
        *(float4*)(wp + 4)  = make_float4(e0[4]*i0, e0[5]*i0, e0[6]*i0, e0[7]*i0);
        *(float4*)(wp + 8)  = make_float4(e1[0]*i1, e1[1]*i1, e1[2]*i1, e1[3]*i1);
        *(float4*)(wp + 12) = make_float4(e1[4]*i1, e1[5]*i1, e1[6]*i1, e1[7]*i1);
    }
}

// ---------------- Kernel B: fused variation + EMA + add ------------------
// Block = (b, chunk, h-slice). 256 threads, thread tid owns ONE column
// h = hs*256 + tid across the chunk's tokens. 1024 blocks -> 16 waves/CU.
__global__ __launch_bounds__(256) void kB_fused(
    const float* __restrict__ x, const float* __restrict__ noise,
    const float* __restrict__ patterns, const float* __restrict__ wts,
    float* __restrict__ out)
{
    __shared__ float wsm[CHUNK * NPAT];   // 4 KB: this chunk's token weights

    const int cid = blockIdx.x;                 // 0 .. B*NCHUNK*HSPLIT-1
    const int hs  = cid & (HSPLIT - 1);
    const int bc  = cid >> 2;                   // b*NCHUNK + c
    const int b   = bc / NCHUNK;
    const int c   = bc % NCHUNK;
    const int t0  = c * CHUNK;
    const size_t tokbase = (size_t)b * T_LEN + t0;
    const int tid = threadIdx.x;
    const int h   = hs * HSL + tid;             // this thread's column

    // stage weights for CHUNK tokens: 128*8 = 1024 floats, 4 per thread
    *(float4*)(wsm + tid * 4) = *(const float4*)(wts + tokbase * NPAT + tid * 4);
    __syncthreads();

    float pat[NPAT];
#pragma unroll
    for (int p = 0; p < NPAT; ++p)
        pat[p] = patterns[p * H_DIM + h];

    // EMA warm-up: 64 truncated-history steps (chunk 0 is exact from t=0)
    float s = 0.0f;
    const int nw = (c == 0) ? 0 : WARM;
    const float* nptr = noise + (tokbase - nw) * (size_t)H_DIM + h;
#pragma unroll 4
    for (int i = 0; i < nw; ++i) {
        s = fmaf(0.9f, s, 0.005f * (*nptr));
        nptr += H_DIM;
    }

    const float* xptr = x + tokbase * H_DIM + h;
    float*       optr = out + tokbase * H_DIM + h;
#pragma unroll 4
    for (int i = 0; i < CHUNK; ++i) {
        const float nv = *nptr;
        const float xv = *xptr;
        s = fmaf(0.9f, s, 0.005f * nv);

        // uniform-address LDS reads (broadcast, conflict-free)
        const float4 wA = *(const float4*)(wsm + i * NPAT);
        const float4 wB = *(const float4*)(wsm + i * NPAT + 4);
        float v = 0.0f;
        v = fmaf(wA.x, pat[0], v);
        v = fmaf(wA.y, pat[1], v);
        v = fmaf(wA.z, pat[2], v);
        v = fmaf(wA.w, pat[3], v);
        v = fmaf(wB.x, pat[4], v);
        v = fmaf(wB.y, pat[5], v);
        v = fmaf(wB.z, pat[6], v);
        v = fmaf(wB.w, pat[7], v);

        *optr = xv + v + s;
        nptr += H_DIM; xptr += H_DIM; optr += H_DIM;
    }
}

extern "C" void kernel_launch(void* const* d_in, const int* in_sizes, int n_in,
                              void* d_out, int out_size, void* d_ws, size_t ws_size,
                              hipStream_t stream) {
    const float* x        = (const float*)d_in[0];  // [B,T,H]
    const float* Wsel     = (const float*)d_in[1];  // [H,8]
    const float* bsel     = (const float*)d_in[2];  // [8]
    const float* patterns = (const float*)d_in[3];  // [8,H]
    const float* noise    = (const float*)d_in[4];  // [B,T,H]
    float* out = (float*)d_out;
    float* wts = (float*)d_ws;                      // [B,T,8] = 1 MB scratch

    const int n_tok = B_DIM * T_LEN;                // 32768
    kA_weights<<<n_tok / 8, 256, 0, stream>>>(x, Wsel, bsel, wts);
    kB_fused<<<B_DIM * NCHUNK * HSPLIT, 256, 0, stream>>>(x, noise, patterns, wts, out);
}